// Round 15
// baseline (247.465 us; speedup 1.0000x reference)
//
#include <hip/hip_runtime.h>
#include <math.h>

#define T_LEN 8192
#define D_IN  1024
#define NH    16
#define NPAD  4224   // 32 (i/f) + 16*256 (k,q,v,o per head), padded
#define NCH   128
#define NGRP  8
#define GSZ   16
#define NPACK 16896  // pack_w blocks
#define NCONV 4096
#define NIF   256

typedef __attribute__((ext_vector_type(8))) _Float16 f16x8;
typedef __attribute__((ext_vector_type(4))) _Float16 f16x4;
typedef __attribute__((ext_vector_type(4))) float f32x4;

// ---- workspace layout (float offsets) ----
static const size_t OFF_WP   = 0;                                  // Wph f16 [NPAD][1024] (2.16M floats)
static const size_t OFF_BG   = 2300000;                            // BgDC [8][65536] f32 + BgDN [8][1024] + Ag [8][16]
static const size_t OFF_BIAS = OFF_WP + (size_t)NPAD * D_IN;       // [NPAD] f32
static const size_t OFF_P    = OFF_BIAS + NPAD;                    // Ph f16 [T][NPAD]
static const size_t OFF_M    = OFF_P + (size_t)T_LEN * NPAD;       // [T][16] f32
static const size_t OFF_DC   = OFF_M + (size_t)T_LEN * NH;         // DCh f16 [NCH][16][64][64]; aliases Xh f16 (consumed first)
static const size_t OFF_DN   = OFF_DC + (size_t)NCH * NH * 64 * 64;
static const size_t OFF_DL   = OFF_DN + (size_t)NCH * NH * 64;
static const size_t OFF_IF   = OFF_DL + (size_t)NCH * NH;          // IFc [T][32] f32

__device__ __forceinline__ void glds16(const void* g, void* l) {
  __builtin_amdgcn_global_load_lds(
      (const __attribute__((address_space(1))) void*)g,
      (__attribute__((address_space(3))) void*)l, 16, 0, 0);
}

// -------------------------------------------------------------------------
// Fused: pack weights [0,NPACK) + X->f16 [NPACK,NPACK+NCONV) +
//        fp32-exact i/f mini-GEMM [NPACK+NCONV, +NIF) -> IFc[T][32].
// -------------------------------------------------------------------------
__global__ __launch_bounds__(256) void pack_conv_if(
    const float* __restrict__ ifw, const float* __restrict__ ow,
    const float* __restrict__ kqw, const float* __restrict__ vw,
    const float* __restrict__ ifb, const float* __restrict__ ob,
    const float* __restrict__ kvqb, _Float16* __restrict__ Wph,
    float* __restrict__ bias,
    const float* __restrict__ X, _Float16* __restrict__ Xh,
    float* __restrict__ IFc) {
  __shared__ float Xs[32 * 72];
  __shared__ float Ws[32 * 68];
  int b = blockIdx.x;
  int tid = threadIdx.x;
  if (b < NPACK) {
    int idx = b * 256 + tid;
    int n = idx >> 10, d = idx & 1023;
    float w = 0.f, bb = 0.f;
    if (n < 32) {
      int h = n >> 1, t = n & 1;
      w = ifw[(h * 2 + t) * D_IN + d];
      bb = ifb[h * 2 + t];
    } else if (n < 4128) {
      int r = n - 32;
      int h = r >> 8, j = r & 255;
      if (j < 64)       { w = kqw[(h * 128 + j) * D_IN + d] * 0.125f; bb = kvqb[(h * 3 + 0) * 64 + j]; }
      else if (j < 128) { w = kqw[(h * 128 + j) * D_IN + d];          bb = kvqb[(h * 3 + 2) * 64 + (j - 64)]; }
      else if (j < 192) { w = vw[(h * 64 + (j - 128)) * D_IN + d];    bb = kvqb[(h * 3 + 1) * 64 + (j - 128)]; }
      else              { w = ow[(h * 64 + (j - 192)) * D_IN + d];    bb = ob[h * 64 + (j - 192)]; }
    }
    Wph[(size_t)n * D_IN + d] = (_Float16)w;
    if (d == 0) bias[n] = bb;
  } else if (b < NPACK + NCONV) {
    int i = ((b - NPACK) * 256 + tid) << 3;
    float4 v0 = *(const float4*)(X + i);
    float4 v1 = *(const float4*)(X + i + 4);
    f16x8 r;
    r[0] = (_Float16)v0.x; r[1] = (_Float16)v0.y; r[2] = (_Float16)v0.z; r[3] = (_Float16)v0.w;
    r[4] = (_Float16)v1.x; r[5] = (_Float16)v1.y; r[6] = (_Float16)v1.z; r[7] = (_Float16)v1.w;
    *(f16x8*)(Xh + i) = r;
  } else {
    int r0 = (b - NPACK - NCONV) << 5;
    int nc = tid & 15;
    int rg = tid >> 4;
    int n0 = nc << 1;
    int sw = ((n0 >> 3) & 3) << 2;
    int sx = ((rg >> 1) & 3) << 2;

    float acc[2][2];
    acc[0][0] = acc[0][1] = acc[1][0] = acc[1][1] = 0.f;

    for (int k0 = 0; k0 < D_IN; k0 += 64) {
      __syncthreads();
#pragma unroll
      for (int i = 0; i < 2; ++i) {
        int fi = (i << 8) + tid;
        int row = fi >> 4, kk = (fi & 15) << 2;
        float4 v = *(const float4*)(X + (size_t)(r0 + row) * D_IN + k0 + kk);
        *(float4*)&Xs[row * 72 + (kk ^ (((row >> 2) & 3) << 2))] = v;
      }
#pragma unroll
      for (int i = 0; i < 2; ++i) {
        int fi = (i << 8) + tid;
        int row = fi >> 4, kk = (fi & 15) << 2;
        float4 v = *(const float4*)(ifw + (size_t)row * D_IN + k0 + kk);
        *(float4*)&Ws[row * 68 + (kk ^ (((row >> 3) & 3) << 2))] = v;
      }
      __syncthreads();
#pragma unroll
      for (int k4 = 0; k4 < 64; k4 += 4) {
        float4 w0 = *(const float4*)&Ws[n0 * 68 + (k4 ^ sw)];
        float4 w1 = *(const float4*)&Ws[(n0 + 1) * 68 + (k4 ^ sw)];
#pragma unroll
        for (int j = 0; j < 2; ++j) {
          float4 xv = *(const float4*)&Xs[((rg << 1) + j) * 72 + (k4 ^ sx)];
          acc[j][0] = fmaf(xv.x, w0.x, acc[j][0]);
          acc[j][0] = fmaf(xv.y, w0.y, acc[j][0]);
          acc[j][0] = fmaf(xv.z, w0.z, acc[j][0]);
          acc[j][0] = fmaf(xv.w, w0.w, acc[j][0]);
          acc[j][1] = fmaf(xv.x, w1.x, acc[j][1]);
          acc[j][1] = fmaf(xv.y, w1.y, acc[j][1]);
          acc[j][1] = fmaf(xv.z, w1.z, acc[j][1]);
          acc[j][1] = fmaf(xv.w, w1.w, acc[j][1]);
        }
      }
    }
    float b0 = ifb[n0], b1 = ifb[n0 + 1];
#pragma unroll
    for (int j = 0; j < 2; ++j) {
      int row = r0 + (rg << 1) + j;
      float2 st; st.x = acc[j][0] + b0; st.y = acc[j][1] + b1;
      *(float2*)(IFc + ((size_t)row << 5) + n0) = st;
    }
  }
}

// -------------------------------------------------------------------------
// f16 MFMA GEMM: Ph = Xh * Wph^T + bias.  R10/R13-proven: 128x128 tile,
// 2-slot dbuf (32KB), T2 both-sides swizzle, XCD-chunked swizzle.
// -------------------------------------------------------------------------
__global__ __launch_bounds__(256) void gemm_f16(
    const _Float16* __restrict__ Xh, const _Float16* __restrict__ Wph,
    const float* __restrict__ bias, _Float16* __restrict__ Ph) {
  __shared__ _Float16 As[2][128 * 32];
  __shared__ _Float16 Bs[2][128 * 32];
  int tid = threadIdx.x;
  int wave = tid >> 6, lane = tid & 63;
  int wgid = blockIdx.x;
  int virt = (wgid & 7) * 264 + (wgid >> 3);
  int mt = virt / 33, nt = virt % 33;
  int m0 = mt << 7, n0 = nt << 7;
  int wr = wave >> 1, wc = wave & 1;

  f32x4 acc[4][4];
  f32x4 zero = {0.f, 0.f, 0.f, 0.f};
#pragma unroll
  for (int i = 0; i < 4; ++i)
#pragma unroll
    for (int j = 0; j < 4; ++j) acc[i][j] = zero;

  int srow = lane >> 2;
  int scol = (((lane & 3) ^ ((lane >> 3) & 3)) << 3);   // pre-swizzled source slot (T2)
  const _Float16* ga = Xh + (size_t)(m0 + wave * 32 + srow) * D_IN + scol;
  const _Float16* gb = Wph + (size_t)(n0 + wave * 32 + srow) * D_IN + scol;
  int lds0 = (wave * 32) * 32;
  int lds1 = (wave * 32 + 16) * 32;

  int fr = lane & 15;
  int fko = (((lane >> 4) ^ ((fr >> 1) & 3)) << 3);     // swizzled frag-read slot (T2)

  glds16(ga, &As[0][lds0]);
  glds16(ga + 16 * D_IN, &As[0][lds1]);
  glds16(gb, &Bs[0][lds0]);
  glds16(gb + 16 * D_IN, &Bs[0][lds1]);
  __syncthreads();

  int cur = 0;
  for (int k0 = 0; k0 < D_IN; k0 += 32) {
    if (k0 + 32 < D_IN) {
      int kn = k0 + 32;
      glds16(ga + kn, &As[cur ^ 1][lds0]);
      glds16(ga + 16 * D_IN + kn, &As[cur ^ 1][lds1]);
      glds16(gb + kn, &Bs[cur ^ 1][lds0]);
      glds16(gb + 16 * D_IN + kn, &Bs[cur ^ 1][lds1]);
    }
    f16x8 a[4], b[4];
#pragma unroll
    for (int mi = 0; mi < 4; ++mi)
      a[mi] = *(const f16x8*)&As[cur][(wr * 64 + mi * 16 + fr) * 32 + fko];
#pragma unroll
    for (int ni = 0; ni < 4; ++ni)
      b[ni] = *(const f16x8*)&Bs[cur][(wc * 64 + ni * 16 + fr) * 32 + fko];
    __builtin_amdgcn_s_setprio(1);
#pragma unroll
    for (int mi = 0; mi < 4; ++mi)
#pragma unroll
      for (int ni = 0; ni < 4; ++ni)
        acc[mi][ni] = __builtin_amdgcn_mfma_f32_16x16x32_f16(a[mi], b[ni], acc[mi][ni], 0, 0, 0);
    __builtin_amdgcn_s_setprio(0);
    __syncthreads();
    cur ^= 1;
  }

  int cr = (lane >> 4) << 2;
  int cc = lane & 15;
#pragma unroll
  for (int mi = 0; mi < 4; ++mi) {
#pragma unroll
    for (int ni = 0; ni < 4; ++ni) {
      int col = n0 + wc * 64 + ni * 16 + cc;
      float bb = bias[col];
      size_t base = (size_t)(m0 + wr * 64 + mi * 16 + cr) * NPAD + col;
#pragma unroll
      for (int r = 0; r < 4; ++r)
        Ph[base + (size_t)r * NPAD] = (_Float16)(acc[mi][ni][r] + bb);
    }
  }
}

// -------------------------------------------------------------------------
// Parallel m-scan (associative (max,+) compose), 16 blocks x 256 threads.
// -------------------------------------------------------------------------
__global__ __launch_bounds__(256) void mscan(const float* __restrict__ IFc, float* __restrict__ M) {
  int h = blockIdx.x;
  int tid = threadIdx.x;
  int lane = tid & 63, wv = tid >> 6;
  int t0 = tid << 5;
  float F = 0.f, I = -1e30f;
#pragma unroll 8
  for (int u = 0; u < 32; ++u) {
    float2 v = *(const float2*)(IFc + ((size_t)(t0 + u) << 5) + (h << 1));
    I = fmaxf(I + v.y, v.x);
    F += v.y;
  }
#pragma unroll
  for (int d = 1; d < 64; d <<= 1) {
    float Fo = __shfl_up(F, d, 64);
    float Io = __shfl_up(I, d, 64);
    if (lane >= d) { I = fmaxf(Io + F, I); F = Fo + F; }
  }
  __shared__ float sF[4], sI[4];
  if (lane == 63) { sF[wv] = F; sI[wv] = I; }
  float Fe = __shfl_up(F, 1, 64);
  float Ie = __shfl_up(I, 1, 64);
  if (lane == 0) { Fe = 0.f; Ie = -1e30f; }
  __syncthreads();
  float Fp = 0.f, Ip = -1e30f;
  for (int w = 0; w < wv; ++w) { Ip = fmaxf(Ip + sF[w], sI[w]); Fp += sF[w]; }
  float Ft = Fp + Fe;
  float It = fmaxf(Ip + Fe, Ie);
  float m = fmaxf(Ft, It);
#pragma unroll 8
  for (int u = 0; u < 32; ++u) {
    float2 v = *(const float2*)(IFc + ((size_t)(t0 + u) << 5) + (h << 1));
    m = fmaxf(v.y + m, v.x);
    M[(size_t)(t0 + u) * NH + h] = m;
  }
}

// -------------------------------------------------------------------------
// D1 (MFMA): DC[a][b] = sum_s (g_s V[s][a]) K[s][b]; DN parallel over 256.
// -------------------------------------------------------------------------
__global__ __launch_bounds__(256) void d1_dc(
    const _Float16* __restrict__ Ph, const float* __restrict__ IFc,
    const float* __restrict__ M,
    _Float16* __restrict__ DCh, float* __restrict__ DN, float* __restrict__ DL) {
  int c = blockIdx.x >> 4, h = blockIdx.x & 15;
  int t0 = c << 6, hb = 32 + (h << 8);
  int tid = threadIdx.x;
  int lane = tid & 63, wave = tid >> 6;
  __shared__ _Float16 Kt[64 * 72];   // Kt[b][s]
  __shared__ _Float16 Vt[64 * 72];   // Vt[a][s]; reused as Dst[a][b] after compute
  __shared__ float gl[64];
#pragma unroll
  for (int i = 0; i < 2; ++i) {
    int fq = (i << 8) + tid;
    int s = fq >> 3, b8 = (fq & 7) << 3;
    const _Float16* row = Ph + (size_t)(t0 + s) * NPAD + hb;
    f16x8 kv = *(const f16x8*)(row + b8);
    f16x8 vv = *(const f16x8*)(row + 128 + b8);
#pragma unroll
    for (int j = 0; j < 8; ++j) {
      Kt[(b8 + j) * 72 + s] = kv[j];
      Vt[(b8 + j) * 72 + s] = vv[j];
    }
  }
  if (tid < 64) {
    float2 iff = *(const float2*)(IFc + ((size_t)(t0 + tid) << 5) + (h << 1));
    float iv = iff.x, fv = iff.y;
    float cs = fv;
#pragma unroll
    for (int dd = 1; dd < 64; dd <<= 1) {
      float o = __shfl_up(cs, dd, 64);
      cs += (tid >= dd) ? o : 0.f;
    }
    float cumL = __shfl(cs, 63, 64);
    float mL = M[(size_t)(t0 + 63) * NH + h];
    gl[tid] = __expf(cumL - cs + iv - mL);
    if (tid == 0) {
      float mstart = (c > 0) ? M[(size_t)(t0 - 1) * NH + h] : 0.f;
      DL[(c << 4) + h] = __expf(mstart + cumL - mL);
    }
  }
  __syncthreads();
  // DN parallel: 4 threads per output b, 16 elems each, 4-lane shfl reduce
  {
    int b = tid >> 2, seg = (tid & 3) << 4;
    float part = 0.f;
#pragma unroll
    for (int j = 0; j < 16; ++j)
      part = fmaf(gl[seg + j], (float)Kt[b * 72 + seg + j], part);
    part += __shfl_xor(part, 1);
    part += __shfl_xor(part, 2);
    if ((tid & 3) == 0) DN[((size_t)(c << 4) + h) * 64 + b] = part;
  }
  int arow = lane & 15;
  int kq = (lane >> 4) << 3;
  int aR = (wave << 4) + arow;
  f16x8 ag0, ag1;
#pragma unroll
  for (int j = 0; j < 8; ++j) {
    ag0[j] = (_Float16)(gl[kq + j] * (float)Vt[aR * 72 + kq + j]);
    ag1[j] = (_Float16)(gl[32 + kq + j] * (float)Vt[aR * 72 + 32 + kq + j]);
  }
  f32x4 accD[4];
  f32x4 zero = {0.f, 0.f, 0.f, 0.f};
#pragma unroll
  for (int n = 0; n < 4; ++n) accD[n] = zero;
#pragma unroll
  for (int n = 0; n < 4; ++n) {
    f16x8 b0 = *(const f16x8*)&Kt[((n << 4) + arow) * 72 + kq];
    f16x8 b1 = *(const f16x8*)&Kt[((n << 4) + arow) * 72 + 32 + kq];
    accD[n] = __builtin_amdgcn_mfma_f32_16x16x32_f16(ag0, b0, accD[n], 0, 0, 0);
    accD[n] = __builtin_amdgcn_mfma_f32_16x16x32_f16(ag1, b1, accD[n], 0, 0, 0);
  }
  __syncthreads();
  int crow = (lane >> 4) << 2, cc = lane & 15;
#pragma unroll
  for (int n = 0; n < 4; ++n)
#pragma unroll
    for (int r = 0; r < 4; ++r)
      Vt[((wave << 4) + crow + r) * 72 + (n << 4) + cc] = (_Float16)accD[n][r];
  __syncthreads();
  size_t base = ((size_t)(c << 4) + h) << 12;
#pragma unroll
  for (int i = 0; i < 2; ++i) {
    int fq = (i << 8) + tid;
    int a = fq >> 3, b8 = (fq & 7) << 3;
    *(f16x8*)(DCh + base + ((size_t)a << 6) + b8) = *(const f16x8*)&Vt[a * 72 + b8];
  }
}

// -------------------------------------------------------------------------
// D2a: per (group, elem) affine aggregates over the group's 16 chunks.
// -------------------------------------------------------------------------
__global__ __launch_bounds__(256) void d2a(
    const _Float16* __restrict__ DCh, const float* __restrict__ DN,
    const float* __restrict__ DL,
    float* __restrict__ BgDC, float* __restrict__ BgDN, float* __restrict__ Ag) {
  int bid = blockIdx.x, tid = threadIdx.x;
  if (bid < 2048) {
    int linear = (bid << 8) + tid;
    int g = linear >> 16, e = linear & 65535;
    int h = e >> 12;
    float carry = 0.f, a = 1.f;
    size_t idx = (size_t)e + ((size_t)g << 4) * 65536;
    float v = (float)DCh[idx];
    for (int u = 0; u < GSZ; ++u) {
      float dl = DL[(((g << 4) + u) << 4) + h];
      float vn = (u < GSZ - 1) ? (float)DCh[idx + 65536] : 0.f;
      carry = fmaf(dl, carry, v);
      a *= dl;
      v = vn;
      idx += 65536;
    }
    BgDC[((size_t)g << 16) + e] = carry;
    if ((e & 4095) == 0) Ag[(g << 4) + h] = a;
  } else {
    int linear = ((bid - 2048) << 8) + tid;
    int g = linear >> 10, e = linear & 1023;
    int h = e >> 6;
    float carry = 0.f;
    size_t idx = (size_t)e + ((size_t)g << 4) * 1024;
    float v = DN[idx];
    for (int u = 0; u < GSZ; ++u) {
      float dl = DL[(((g << 4) + u) << 4) + h];
      float vn = (u < GSZ - 1) ? DN[idx + 1024] : 0.f;
      carry = fmaf(dl, carry, v);
      v = vn;
      idx += 1024;
    }
    BgDN[(g << 10) + e] = carry;
  }
}

// -------------------------------------------------------------------------
// D2c: inline exclusive group-prefix then in-place exclusive carries.
// -------------------------------------------------------------------------
__global__ __launch_bounds__(256) void d2c(
    _Float16* __restrict__ DCh, float* __restrict__ DN,
    const float* __restrict__ DL,
    const float* __restrict__ BgDC, const float* __restrict__ BgDN,
    const float* __restrict__ Ag) {
  int bid = blockIdx.x, tid = threadIdx.x;
  if (bid < 2048) {
    int linear = (bid << 8) + tid;
    int g = linear >> 16, e = linear & 65535;
    int h = e >> 12;
    float P = 0.f;
    for (int gp = 0; gp < g; ++gp)
      P = fmaf(Ag[(gp << 4) + h], P, BgDC[((size_t)gp << 16) + e]);
    float carry = P;
    size_t idx = (size_t)e + ((size_t)g << 4) * 65536;
    float v = (float)DCh[idx];
    for (int u = 0; u < GSZ; ++u) {
      float dl = DL[(((g << 4) + u) << 4) + h];
      float vn = (u < GSZ - 1) ? (float)DCh[idx + 65536] : 0.f;
      DCh[idx] = (_Float16)carry;
      carry = fmaf(dl, carry, v);
      v = vn;
      idx += 65536;
    }
  } else {
    int linear = ((bid - 2048) << 8) + tid;
    int g = linear >> 10, e = linear & 1023;
    int h = e >> 6;
    float P = 0.f;
    for (int gp = 0; gp < g; ++gp)
      P = fmaf(Ag[(gp << 4) + h], P, BgDN[(gp << 10) + e]);
    float carry = P;
    size_t idx = (size_t)e + ((size_t)g << 4) * 1024;
    float v = DN[idx];
    for (int u = 0; u < GSZ; ++u) {
      float dl = DL[(((g << 4) + u) << 4) + h];
      float vn = (u < GSZ - 1) ? DN[idx + 1024] : 0.f;
      DN[idx] = carry;
      carry = fmaf(dl, carry, v);
      v = vn;
      idx += 1024;
    }
  }
}

// -------------------------------------------------------------------------
// D3 (MFMA): per (chunk,head) outputs.  LDS diet (Pl aliases Kh, O direct).
// -------------------------------------------------------------------------
__global__ __launch_bounds__(256) void d3_out(
    const _Float16* __restrict__ Ph, const float* __restrict__ IFc,
    const float* __restrict__ M,
    const _Float16* __restrict__ CS, const float* __restrict__ NS,
    float* __restrict__ out) {
  int c = blockIdx.x >> 4, h = blockIdx.x & 15;
  int t0 = c << 6, hb = 32 + (h << 8);
  int tid = threadIdx.x;
  int lane = tid & 63, wave = tid >> 6;
  __shared__ _Float16 Kh[64 * 72];   // K; overwritten with gated P after QK^T
  __shared__ _Float16 Qh[64 * 72];
  __shared__ _Float16 Vt[64 * 72];
  __shared__ _Float16 Ch[64 * 72];
  __shared__ float cf[64], il[64], ml[64], dl[64], nq[64], nsl[64];

#pragma unroll
  for (int i = 0; i < 2; ++i) {
    int fq = (i << 8) + tid;
    int s = fq >> 3, b8 = (fq & 7) << 3;
    const _Float16* row = Ph + (size_t)(t0 + s) * NPAD + hb;
    f16x8 kv = *(const f16x8*)(row + b8);
    f16x8 qv = *(const f16x8*)(row + 64 + b8);
    f16x8 vv = *(const f16x8*)(row + 128 + b8);
    f16x8 cv = *(const f16x8*)(CS + ((((size_t)(c << 4)) + h) << 12) + ((size_t)s << 6) + b8);
    *(f16x8*)&Kh[s * 72 + b8] = kv;
    *(f16x8*)&Qh[s * 72 + b8] = qv;
    *(f16x8*)&Ch[s * 72 + b8] = cv;
#pragma unroll
    for (int j = 0; j < 8; ++j) Vt[(b8 + j) * 72 + s] = vv[j];
  }
  __syncthreads();

  float iv = 0.f, mt = 0.f, cs = 0.f;
  if (tid < 64) {
    float2 iff = *(const float2*)(IFc + ((size_t)(t0 + tid) << 5) + (h << 1));
    iv = iff.x;
    float fv = iff.y;
    mt = M[(size_t)(t0 + tid) * NH + h];
    nsl[tid] = NS[((size_t)(c << 4) + h) * 64 + tid];
    cs = fv;
#pragma unroll
    for (int dd = 1; dd < 64; dd <<= 1) {
      float o = __shfl_up(cs, dd, 64);
      cs += (tid >= dd) ? o : 0.f;
    }
  }
  __syncthreads();
  if (tid < 64) {
    cf[tid] = cs; il[tid] = iv; ml[tid] = mt;
    float mstart = (c > 0) ? M[(size_t)(t0 - 1) * NH + h] : 0.f;
    dl[tid] = __expf(mstart + cs - mt);
  }
  // nq parallel: 4 threads per row, 16 elems each, 4-lane shfl reduce
  {
    int r = tid >> 2, seg = (tid & 3) << 4;
    float part = 0.f;
#pragma unroll
    for (int j = 0; j < 16; ++j)
      part = fmaf(nsl[seg + j], (float)Qh[r * 72 + seg + j], part);
    part += __shfl_xor(part, 1);
    part += __shfl_xor(part, 2);
    if ((tid & 3) == 0) nq[r] = part;
  }
  __syncthreads();

  int band = wave << 4;
  int arow = lane & 15;
  int kq = (lane >> 4) << 3;
  int crow = (lane >> 4) << 2;

  f16x8 aq0 = *(const f16x8*)&Qh[(band + arow) * 72 + kq];
  f16x8 aq1 = *(const f16x8*)&Qh[(band + arow) * 72 + 32 + kq];

  f32x4 S[4];
  f32x4 zero = {0.f, 0.f, 0.f, 0.f};
#pragma unroll
  for (int n = 0; n < 4; ++n) S[n] = zero;
#pragma unroll
  for (int n = 0; n < 4; ++n) {
    f16x8 b0 = *(const f16x8*)&Kh[((n << 4) + arow) * 72 + kq];
    f16x8 b1 = *(const f16x8*)&Kh[((n << 4) + arow) * 72 + 32 + kq];
    S[n] = __builtin_amdgcn_mfma_f32_16x16x32_f16(aq0, b0, S[n], 0, 0, 0);
    S[n] = __builtin_amdgcn_mfma_f32_16x16x32_f16(aq1, b1, S[n], 0, 0, 0);
  }
  __syncthreads();   // all Kh reads done; Kh region now reusable for P

  float cft[4], mlt[4];
#pragma unroll
  for (int r = 0; r < 4; ++r) {
    int t = band + crow + r;
    cft[r] = cf[t]; mlt[r] = ml[t];
  }
  float rsum[4] = {0.f, 0.f, 0.f, 0.f};
#pragma unroll
  for (int n = 0; n < 4; ++n) {
    int s = (n << 4) + arow;
    float cfs = cf[s], ils = il[s];
#pragma unroll
    for (int r = 0; r < 4; ++r) {
      int t = band + crow + r;
      float w = (s <= t) ? __expf(cft[r] - cfs + ils - mlt[r]) : 0.f;
      float p = S[n][r] * w;
      rsum[r] += p;
      Kh[t * 72 + s] = (_Float16)p;   // P into Kh region
    }
  }
#pragma unroll
  for (int r = 0; r < 4; ++r) {
    float p = rsum[r];
    p += __shfl_xor(p, 1);
    p += __shfl_xor(p, 2);
    p += __shfl_xor(p, 4);
    p += __shfl_xor(p, 8);
    rsum[r] = p;
  }
  __syncthreads();

  f16x8 ap0 = *(const f16x8*)&Kh[(band + arow) * 72 + kq];
  f16x8 ap1 = *(const f16x8*)&Kh[(band + arow) * 72 + 32 + kq];
  f32x4 H[4], I[4];
#pragma unroll
  for (int n = 0; n < 4; ++n) { H[n] = zero; I[n] = zero; }
#pragma unroll
  for (int n = 0; n < 4; ++n) {
    f16x8 bv0 = *(const f16x8*)&Vt[((n << 4) + arow) * 72 + kq];
    f16x8 bv1 = *(const f16x8*)&Vt[((n << 4) + arow) * 72 + 32 + kq];
    H[n] = __builtin_amdgcn_mfma_f32_16x16x32_f16(ap0, bv0, H[n], 0, 0, 0);
    H[n] = __builtin_amdgcn_mfma_f32_16x16x32_f16(ap1, bv1, H[n], 0, 0, 0);
    f16x8 bc0 = *(const f16x8*)&Ch[((n << 4) + arow) * 72 + kq];
    f16x8 bc1 = *(const f16x8*)&Ch[((n << 4) + arow) * 72 + 32 + kq];
    I[n] = __builtin_amdgcn_mfma_f32_16x16x32_f16(aq0, bc0, I[n], 0, 0, 0);
    I[n] = __builtin_amdgcn_mfma_f32_16x16x32_f16(aq1, bc1, I[n], 0, 0, 0);
  }

#pragma unroll
  for (int r = 0; r < 4; ++r) {
    int t = band + crow + r;
    float dt = dl[t];
    float dn = fmaf(dt, nq[t], rsum[r]);
    float rinv = 1.f / fmaxf(fabsf(dn), 1.f);
    float* orow = out + (size_t)(t0 + t) * 1024 + (h << 6);
    const _Float16* og = Ph + (size_t)(t0 + t) * NPAD + hb + 192;
#pragma unroll
    for (int n = 0; n < 4; ++n) {
      int a = (n << 4) + arow;
      float o = 1.f / (1.f + __expf(-(float)og[a]));
      orow[a] = o * (fmaf(dt, I[n][r], H[n][r]) * rinv);
    }
  }
}

// -------------------------------------------------------------------------
extern "C" void kernel_launch(void* const* d_in, const int* in_sizes, int n_in,
                              void* d_out, int out_size, void* d_ws, size_t ws_size,
                              hipStream_t stream) {
  const float* xs   = (const float*)d_in[0];
  const float* ifw  = (const float*)d_in[1];
  const float* ow   = (const float*)d_in[2];
  const float* kqw  = (const float*)d_in[3];
  const float* vw   = (const float*)d_in[4];
  const float* ifb  = (const float*)d_in[5];
  const float* ob   = (const float*)d_in[6];
  const float* kvqb = (const float*)d_in[7];
  float* ws   = (float*)d_ws;
  _Float16* Wph = (_Float16*)(ws + OFF_WP);
  float* BgDC = ws + OFF_BG;
  float* BgDN = BgDC + (size_t)NGRP * 65536;
  float* Ag   = BgDN + (size_t)NGRP * 1024;
  float* bias = ws + OFF_BIAS;
  _Float16* Phm = (_Float16*)(ws + OFF_P);
  float* Mm   = ws + OFF_M;
  _Float16* DCh = (_Float16*)(ws + OFF_DC);
  _Float16* Xh  = (_Float16*)(ws + OFF_DC);  // alias: consumed by gemm before d1 writes DCh
  float* DN   = ws + OFF_DN;
  float* DL   = ws + OFF_DL;
  float* IFc  = ws + OFF_IF;
  float* outp = (float*)d_out;

  hipLaunchKernelGGL(pack_conv_if, dim3(NPACK + NCONV + NIF), dim3(256), 0, stream,
                     ifw, ow, kqw, vw, ifb, ob, kvqb, Wph, bias, xs, Xh, IFc);
  hipLaunchKernelGGL(gemm_f16, dim3(33 * 64), dim3(256), 0, stream,
                     Xh, Wph, bias, Phm);
  hipLaunchKernelGGL(mscan, dim3(NH), dim3(256), 0, stream, IFc, Mm);
  hipLaunchKernelGGL(d1_dc, dim3(NCH * NH), dim3(256), 0, stream, Phm, IFc, Mm, DCh, DN, DL);
  hipLaunchKernelGGL(d2a, dim3(2080), dim3(256), 0, stream, DCh, DN, DL, BgDC, BgDN, Ag);
  hipLaunchKernelGGL(d2c, dim3(2080), dim3(256), 0, stream, DCh, DN, DL, BgDC, BgDN, Ag);
  hipLaunchKernelGGL(d3_out, dim3(NCH * NH), dim3(256), 0, stream, Phm, IFc, Mm, DCh, DN, outp);
}

// Round 16
// 208.848 us; speedup vs baseline: 1.1849x; 1.1849x over previous
//
#include <hip/hip_runtime.h>
#include <math.h>

#define T_LEN 8192
#define D_IN  1024
#define NH    16
#define NPAD  4224   // 32 (i/f) + 16*256 (k,q,v,o per head), padded
#define NCH   128
#define NGRP  8
#define GSZ   16
#define NPACK 16896  // pack_w blocks
#define NCONV 4096

typedef __attribute__((ext_vector_type(8))) _Float16 f16x8;
typedef __attribute__((ext_vector_type(4))) _Float16 f16x4;
typedef __attribute__((ext_vector_type(4))) float f32x4;

// ---- workspace layout (float offsets) ----
static const size_t OFF_WP   = 0;                                  // Wph f16 [NPAD][1024] (2.16M floats)
static const size_t OFF_BG   = 2300000;                            // BgDC [8][65536] f32 + BgDN [8][1024] + Ag [8][16]
static const size_t OFF_BIAS = OFF_WP + (size_t)NPAD * D_IN;       // [NPAD] f32
static const size_t OFF_P    = OFF_BIAS + NPAD;                    // Ph f16 [T][NPAD]
static const size_t OFF_M    = OFF_P + (size_t)T_LEN * NPAD;       // [T][16] f32
static const size_t OFF_DC   = OFF_M + (size_t)T_LEN * NH;         // DCh f16 [NCH][16][64][64]; aliases Xh f16 (consumed first)
static const size_t OFF_DN   = OFF_DC + (size_t)NCH * NH * 64 * 64;
static const size_t OFF_DL   = OFF_DN + (size_t)NCH * NH * 64;
static const size_t OFF_IF   = OFF_DL + (size_t)NCH * NH;          // IFc [T][32] f32

__device__ __forceinline__ void glds16(const void* g, void* l) {
  __builtin_amdgcn_global_load_lds(
      (const __attribute__((address_space(1))) void*)g,
      (__attribute__((address_space(3))) void*)l, 16, 0, 0);
}

// -------------------------------------------------------------------------
// Fused: pack weights (blocks [0,NPACK)) + X->f16 (blocks [NPACK,NPACK+NCONV))
// -------------------------------------------------------------------------
__global__ __launch_bounds__(256) void pack_conv(
    const float* __restrict__ ifw, const float* __restrict__ ow,
    const float* __restrict__ kqw, const float* __restrict__ vw,
    const float* __restrict__ ifb, const float* __restrict__ ob,
    const float* __restrict__ kvqb, _Float16* __restrict__ Wph,
    float* __restrict__ bias,
    const float* __restrict__ X, _Float16* __restrict__ Xh) {
  int b = blockIdx.x;
  if (b < NPACK) {
    int idx = b * 256 + threadIdx.x;
    int n = idx >> 10, d = idx & 1023;
    float w = 0.f, bb = 0.f;
    if (n < 32) {
      int h = n >> 1, t = n & 1;
      w = ifw[(h * 2 + t) * D_IN + d];
      bb = ifb[h * 2 + t];
    } else if (n < 4128) {
      int r = n - 32;
      int h = r >> 8, j = r & 255;
      if (j < 64)       { w = kqw[(h * 128 + j) * D_IN + d] * 0.125f; bb = kvqb[(h * 3 + 0) * 64 + j]; }
      else if (j < 128) { w = kqw[(h * 128 + j) * D_IN + d];          bb = kvqb[(h * 3 + 2) * 64 + (j - 64)]; }
      else if (j < 192) { w = vw[(h * 64 + (j - 128)) * D_IN + d];    bb = kvqb[(h * 3 + 1) * 64 + (j - 128)]; }
      else              { w = ow[(h * 64 + (j - 192)) * D_IN + d];    bb = ob[h * 64 + (j - 192)]; }
    }
    Wph[(size_t)n * D_IN + d] = (_Float16)w;
    if (d == 0) bias[n] = bb;
  } else {
    int i = ((b - NPACK) * 256 + threadIdx.x) << 3;
    float4 v0 = *(const float4*)(X + i);
    float4 v1 = *(const float4*)(X + i + 4);
    f16x8 r;
    r[0] = (_Float16)v0.x; r[1] = (_Float16)v0.y; r[2] = (_Float16)v0.z; r[3] = (_Float16)v0.w;
    r[4] = (_Float16)v1.x; r[5] = (_Float16)v1.y; r[6] = (_Float16)v1.z; r[7] = (_Float16)v1.w;
    *(f16x8*)(Xh + i) = r;
  }
}

// -------------------------------------------------------------------------
// f16 MFMA GEMM: Ph = Xh * Wph^T + bias.  R10/R13-proven: 128x128 tile,
// 2-slot dbuf (32KB), T2 both-sides swizzle, XCD-chunked swizzle.
// -------------------------------------------------------------------------
__global__ __launch_bounds__(256) void gemm_f16(
    const _Float16* __restrict__ Xh, const _Float16* __restrict__ Wph,
    const float* __restrict__ bias, _Float16* __restrict__ Ph) {
  __shared__ _Float16 As[2][128 * 32];
  __shared__ _Float16 Bs[2][128 * 32];
  int tid = threadIdx.x;
  int wave = tid >> 6, lane = tid & 63;
  int wgid = blockIdx.x;
  int virt = (wgid & 7) * 264 + (wgid >> 3);
  int mt = virt / 33, nt = virt % 33;
  int m0 = mt << 7, n0 = nt << 7;
  int wr = wave >> 1, wc = wave & 1;

  f32x4 acc[4][4];
  f32x4 zero = {0.f, 0.f, 0.f, 0.f};
#pragma unroll
  for (int i = 0; i < 4; ++i)
#pragma unroll
    for (int j = 0; j < 4; ++j) acc[i][j] = zero;

  int srow = lane >> 2;
  int scol = (((lane & 3) ^ ((lane >> 3) & 3)) << 3);   // pre-swizzled source slot (T2)
  const _Float16* ga = Xh + (size_t)(m0 + wave * 32 + srow) * D_IN + scol;
  const _Float16* gb = Wph + (size_t)(n0 + wave * 32 + srow) * D_IN + scol;
  int lds0 = (wave * 32) * 32;
  int lds1 = (wave * 32 + 16) * 32;

  int fr = lane & 15;
  int fko = (((lane >> 4) ^ ((fr >> 1) & 3)) << 3);     // swizzled frag-read slot (T2)

  glds16(ga, &As[0][lds0]);
  glds16(ga + 16 * D_IN, &As[0][lds1]);
  glds16(gb, &Bs[0][lds0]);
  glds16(gb + 16 * D_IN, &Bs[0][lds1]);
  __syncthreads();

  int cur = 0;
  for (int k0 = 0; k0 < D_IN; k0 += 32) {
    if (k0 + 32 < D_IN) {
      int kn = k0 + 32;
      glds16(ga + kn, &As[cur ^ 1][lds0]);
      glds16(ga + 16 * D_IN + kn, &As[cur ^ 1][lds1]);
      glds16(gb + kn, &Bs[cur ^ 1][lds0]);
      glds16(gb + 16 * D_IN + kn, &Bs[cur ^ 1][lds1]);
    }
    f16x8 a[4], b[4];
#pragma unroll
    for (int mi = 0; mi < 4; ++mi)
      a[mi] = *(const f16x8*)&As[cur][(wr * 64 + mi * 16 + fr) * 32 + fko];
#pragma unroll
    for (int ni = 0; ni < 4; ++ni)
      b[ni] = *(const f16x8*)&Bs[cur][(wc * 64 + ni * 16 + fr) * 32 + fko];
    __builtin_amdgcn_s_setprio(1);
#pragma unroll
    for (int mi = 0; mi < 4; ++mi)
#pragma unroll
      for (int ni = 0; ni < 4; ++ni)
        acc[mi][ni] = __builtin_amdgcn_mfma_f32_16x16x32_f16(a[mi], b[ni], acc[mi][ni], 0, 0, 0);
    __builtin_amdgcn_s_setprio(0);
    __syncthreads();
    cur ^= 1;
  }

  int cr = (lane >> 4) << 2;
  int cc = lane & 15;
#pragma unroll
  for (int mi = 0; mi < 4; ++mi) {
#pragma unroll
    for (int ni = 0; ni < 4; ++ni) {
      int col = n0 + wc * 64 + ni * 16 + cc;
      float bb = bias[col];
      size_t base = (size_t)(m0 + wr * 64 + mi * 16 + cr) * NPAD + col;
#pragma unroll
      for (int r = 0; r < 4; ++r)
        Ph[base + (size_t)r * NPAD] = (_Float16)(acc[mi][ni][r] + bb);
    }
  }
}

// -------------------------------------------------------------------------
// fp32 exact i/f columns, LDS-tiled -> IFc[T][32].  BM=32, 256 blocks.
// -------------------------------------------------------------------------
__global__ __launch_bounds__(256) void gemm_if(
    const float* __restrict__ X, const float* __restrict__ ifw,
    const float* __restrict__ ifb, float* __restrict__ IFc) {
  __shared__ float Xs[32 * 72];
  __shared__ float Ws[32 * 68];
  int tid = threadIdx.x;
  int r0 = blockIdx.x << 5;
  int nc = tid & 15;
  int rg = tid >> 4;
  int n0 = nc << 1;
  int sw = ((n0 >> 3) & 3) << 2;
  int sx = ((rg >> 1) & 3) << 2;

  float acc[2][2];
  acc[0][0] = acc[0][1] = acc[1][0] = acc[1][1] = 0.f;

  for (int k0 = 0; k0 < D_IN; k0 += 64) {
    __syncthreads();
#pragma unroll
    for (int i = 0; i < 2; ++i) {
      int fi = (i << 8) + tid;
      int row = fi >> 4, kk = (fi & 15) << 2;
      float4 v = *(const float4*)(X + (size_t)(r0 + row) * D_IN + k0 + kk);
      *(float4*)&Xs[row * 72 + (kk ^ (((row >> 2) & 3) << 2))] = v;
    }
#pragma unroll
    for (int i = 0; i < 2; ++i) {
      int fi = (i << 8) + tid;
      int row = fi >> 4, kk = (fi & 15) << 2;
      float4 v = *(const float4*)(ifw + (size_t)row * D_IN + k0 + kk);
      *(float4*)&Ws[row * 68 + (kk ^ (((row >> 3) & 3) << 2))] = v;
    }
    __syncthreads();
#pragma unroll
    for (int k4 = 0; k4 < 64; k4 += 4) {
      float4 w0 = *(const float4*)&Ws[n0 * 68 + (k4 ^ sw)];
      float4 w1 = *(const float4*)&Ws[(n0 + 1) * 68 + (k4 ^ sw)];
#pragma unroll
      for (int j = 0; j < 2; ++j) {
        float4 xv = *(const float4*)&Xs[((rg << 1) + j) * 72 + (k4 ^ sx)];
        acc[j][0] = fmaf(xv.x, w0.x, acc[j][0]);
        acc[j][0] = fmaf(xv.y, w0.y, acc[j][0]);
        acc[j][0] = fmaf(xv.z, w0.z, acc[j][0]);
        acc[j][0] = fmaf(xv.w, w0.w, acc[j][0]);
        acc[j][1] = fmaf(xv.x, w1.x, acc[j][1]);
        acc[j][1] = fmaf(xv.y, w1.y, acc[j][1]);
        acc[j][1] = fmaf(xv.z, w1.z, acc[j][1]);
        acc[j][1] = fmaf(xv.w, w1.w, acc[j][1]);
      }
    }
  }
  float b0 = ifb[n0], b1 = ifb[n0 + 1];
#pragma unroll
  for (int j = 0; j < 2; ++j) {
    int row = r0 + (rg << 1) + j;
    float2 st; st.x = acc[j][0] + b0; st.y = acc[j][1] + b1;
    *(float2*)(IFc + ((size_t)row << 5) + n0) = st;
  }
}

// -------------------------------------------------------------------------
// Parallel m-scan (associative (max,+) compose), 16 blocks x 256 threads.
// -------------------------------------------------------------------------
__global__ __launch_bounds__(256) void mscan(const float* __restrict__ IFc, float* __restrict__ M) {
  int h = blockIdx.x;
  int tid = threadIdx.x;
  int lane = tid & 63, wv = tid >> 6;
  int t0 = tid << 5;
  float F = 0.f, I = -1e30f;
#pragma unroll 8
  for (int u = 0; u < 32; ++u) {
    float2 v = *(const float2*)(IFc + ((size_t)(t0 + u) << 5) + (h << 1));
    I = fmaxf(I + v.y, v.x);
    F += v.y;
  }
#pragma unroll
  for (int d = 1; d < 64; d <<= 1) {
    float Fo = __shfl_up(F, d, 64);
    float Io = __shfl_up(I, d, 64);
    if (lane >= d) { I = fmaxf(Io + F, I); F = Fo + F; }
  }
  __shared__ float sF[4], sI[4];
  if (lane == 63) { sF[wv] = F; sI[wv] = I; }
  float Fe = __shfl_up(F, 1, 64);
  float Ie = __shfl_up(I, 1, 64);
  if (lane == 0) { Fe = 0.f; Ie = -1e30f; }
  __syncthreads();
  float Fp = 0.f, Ip = -1e30f;
  for (int w = 0; w < wv; ++w) { Ip = fmaxf(Ip + sF[w], sI[w]); Fp += sF[w]; }
  float Ft = Fp + Fe;
  float It = fmaxf(Ip + Fe, Ie);
  float m = fmaxf(Ft, It);
#pragma unroll 8
  for (int u = 0; u < 32; ++u) {
    float2 v = *(const float2*)(IFc + ((size_t)(t0 + u) << 5) + (h << 1));
    m = fmaxf(v.y + m, v.x);
    M[(size_t)(t0 + u) * NH + h] = m;
  }
}

// -------------------------------------------------------------------------
// D1 (MFMA): DC[a][b] = sum_s (g_s V[s][a]) K[s][b]; DN parallel over 256.
// -------------------------------------------------------------------------
__global__ __launch_bounds__(256) void d1_dc(
    const _Float16* __restrict__ Ph, const float* __restrict__ IFc,
    const float* __restrict__ M,
    _Float16* __restrict__ DCh, float* __restrict__ DN, float* __restrict__ DL) {
  int c = blockIdx.x >> 4, h = blockIdx.x & 15;
  int t0 = c << 6, hb = 32 + (h << 8);
  int tid = threadIdx.x;
  int lane = tid & 63, wave = tid >> 6;
  __shared__ _Float16 Kt[64 * 72];   // Kt[b][s]
  __shared__ _Float16 Vt[64 * 72];   // Vt[a][s]; reused as Dst[a][b] after compute
  __shared__ float gl[64];
#pragma unroll
  for (int i = 0; i < 2; ++i) {
    int fq = (i << 8) + tid;
    int s = fq >> 3, b8 = (fq & 7) << 3;
    const _Float16* row = Ph + (size_t)(t0 + s) * NPAD + hb;
    f16x8 kv = *(const f16x8*)(row + b8);
    f16x8 vv = *(const f16x8*)(row + 128 + b8);
#pragma unroll
    for (int j = 0; j < 8; ++j) {
      Kt[(b8 + j) * 72 + s] = kv[j];
      Vt[(b8 + j) * 72 + s] = vv[j];
    }
  }
  if (tid < 64) {
    float2 iff = *(const float2*)(IFc + ((size_t)(t0 + tid) << 5) + (h << 1));
    float iv = iff.x, fv = iff.y;
    float cs = fv;
#pragma unroll
    for (int dd = 1; dd < 64; dd <<= 1) {
      float o = __shfl_up(cs, dd, 64);
      cs += (tid >= dd) ? o : 0.f;
    }
    float cumL = __shfl(cs, 63, 64);
    float mL = M[(size_t)(t0 + 63) * NH + h];
    gl[tid] = __expf(cumL - cs + iv - mL);
    if (tid == 0) {
      float mstart = (c > 0) ? M[(size_t)(t0 - 1) * NH + h] : 0.f;
      DL[(c << 4) + h] = __expf(mstart + cumL - mL);
    }
  }
  __syncthreads();
  // DN parallel: 4 threads per output b, 16 elems each, 4-lane shfl reduce
  {
    int b = tid >> 2, seg = (tid & 3) << 4;
    float part = 0.f;
#pragma unroll
    for (int j = 0; j < 16; ++j)
      part = fmaf(gl[seg + j], (float)Kt[b * 72 + seg + j], part);
    part += __shfl_xor(part, 1);
    part += __shfl_xor(part, 2);
    if ((tid & 3) == 0) DN[((size_t)(c << 4) + h) * 64 + b] = part;
  }
  int arow = lane & 15;
  int kq = (lane >> 4) << 3;
  int aR = (wave << 4) + arow;
  f16x8 ag0, ag1;
#pragma unroll
  for (int j = 0; j < 8; ++j) {
    ag0[j] = (_Float16)(gl[kq + j] * (float)Vt[aR * 72 + kq + j]);
    ag1[j] = (_Float16)(gl[32 + kq + j] * (float)Vt[aR * 72 + 32 + kq + j]);
  }
  f32x4 accD[4];
  f32x4 zero = {0.f, 0.f, 0.f, 0.f};
#pragma unroll
  for (int n = 0; n < 4; ++n) accD[n] = zero;
#pragma unroll
  for (int n = 0; n < 4; ++n) {
    f16x8 b0 = *(const f16x8*)&Kt[((n << 4) + arow) * 72 + kq];
    f16x8 b1 = *(const f16x8*)&Kt[((n << 4) + arow) * 72 + 32 + kq];
    accD[n] = __builtin_amdgcn_mfma_f32_16x16x32_f16(ag0, b0, accD[n], 0, 0, 0);
    accD[n] = __builtin_amdgcn_mfma_f32_16x16x32_f16(ag1, b1, accD[n], 0, 0, 0);
  }
  __syncthreads();
  int crow = (lane >> 4) << 2, cc = lane & 15;
#pragma unroll
  for (int n = 0; n < 4; ++n)
#pragma unroll
    for (int r = 0; r < 4; ++r)
      Vt[((wave << 4) + crow + r) * 72 + (n << 4) + cc] = (_Float16)accD[n][r];
  __syncthreads();
  size_t base = ((size_t)(c << 4) + h) << 12;
#pragma unroll
  for (int i = 0; i < 2; ++i) {
    int fq = (i << 8) + tid;
    int a = fq >> 3, b8 = (fq & 7) << 3;
    *(f16x8*)(DCh + base + ((size_t)a << 6) + b8) = *(const f16x8*)&Vt[a * 72 + b8];
  }
}

// -------------------------------------------------------------------------
// D2a: per (group, elem) affine aggregates over the group's 16 chunks.
// -------------------------------------------------------------------------
__global__ __launch_bounds__(256) void d2a(
    const _Float16* __restrict__ DCh, const float* __restrict__ DN,
    const float* __restrict__ DL,
    float* __restrict__ BgDC, float* __restrict__ BgDN, float* __restrict__ Ag) {
  int bid = blockIdx.x, tid = threadIdx.x;
  if (bid < 2048) {
    int linear = (bid << 8) + tid;
    int g = linear >> 16, e = linear & 65535;
    int h = e >> 12;
    float carry = 0.f, a = 1.f;
    size_t idx = (size_t)e + ((size_t)g << 4) * 65536;
    float v = (float)DCh[idx];
    for (int u = 0; u < GSZ; ++u) {
      float dl = DL[(((g << 4) + u) << 4) + h];
      float vn = (u < GSZ - 1) ? (float)DCh[idx + 65536] : 0.f;
      carry = fmaf(dl, carry, v);
      a *= dl;
      v = vn;
      idx += 65536;
    }
    BgDC[((size_t)g << 16) + e] = carry;
    if ((e & 4095) == 0) Ag[(g << 4) + h] = a;
  } else {
    int linear = ((bid - 2048) << 8) + tid;
    int g = linear >> 10, e = linear & 1023;
    int h = e >> 6;
    float carry = 0.f;
    size_t idx = (size_t)e + ((size_t)g << 4) * 1024;
    float v = DN[idx];
    for (int u = 0; u < GSZ; ++u) {
      float dl = DL[(((g << 4) + u) << 4) + h];
      float vn = (u < GSZ - 1) ? DN[idx + 1024] : 0.f;
      carry = fmaf(dl, carry, v);
      v = vn;
      idx += 1024;
    }
    BgDN[(g << 10) + e] = carry;
  }
}

// -------------------------------------------------------------------------
// D2c: inline exclusive group-prefix then in-place exclusive carries.
// -------------------------------------------------------------------------
__global__ __launch_bounds__(256) void d2c(
    _Float16* __restrict__ DCh, float* __restrict__ DN,
    const float* __restrict__ DL,
    const float* __restrict__ BgDC, const float* __restrict__ BgDN,
    const float* __restrict__ Ag) {
  int bid = blockIdx.x, tid = threadIdx.x;
  if (bid < 2048) {
    int linear = (bid << 8) + tid;
    int g = linear >> 16, e = linear & 65535;
    int h = e >> 12;
    float P = 0.f;
    for (int gp = 0; gp < g; ++gp)
      P = fmaf(Ag[(gp << 4) + h], P, BgDC[((size_t)gp << 16) + e]);
    float carry = P;
    size_t idx = (size_t)e + ((size_t)g << 4) * 65536;
    float v = (float)DCh[idx];
    for (int u = 0; u < GSZ; ++u) {
      float dl = DL[(((g << 4) + u) << 4) + h];
      float vn = (u < GSZ - 1) ? (float)DCh[idx + 65536] : 0.f;
      DCh[idx] = (_Float16)carry;
      carry = fmaf(dl, carry, v);
      v = vn;
      idx += 65536;
    }
  } else {
    int linear = ((bid - 2048) << 8) + tid;
    int g = linear >> 10, e = linear & 1023;
    int h = e >> 6;
    float P = 0.f;
    for (int gp = 0; gp < g; ++gp)
      P = fmaf(Ag[(gp << 4) + h], P, BgDN[(gp << 10) + e]);
    float carry = P;
    size_t idx = (size_t)e + ((size_t)g << 4) * 1024;
    float v = DN[idx];
    for (int u = 0; u < GSZ; ++u) {
      float dl = DL[(((g << 4) + u) << 4) + h];
      float vn = (u < GSZ - 1) ? DN[idx + 1024] : 0.f;
      DN[idx] = carry;
      carry = fmaf(dl, carry, v);
      v = vn;
      idx += 1024;
    }
  }
}

// -------------------------------------------------------------------------
// D3 (MFMA): per (chunk,head) outputs.  LDS diet (Pl aliases Kh, O direct).
// -------------------------------------------------------------------------
__global__ __launch_bounds__(256) void d3_out(
    const _Float16* __restrict__ Ph, const float* __restrict__ IFc,
    const float* __restrict__ M,
    const _Float16* __restrict__ CS, const float* __restrict__ NS,
    float* __restrict__ out) {
  int c = blockIdx.x >> 4, h = blockIdx.x & 15;
  int t0 = c << 6, hb = 32 + (h << 8);
  int tid = threadIdx.x;
  int lane = tid & 63, wave = tid >> 6;
  __shared__ _Float16 Kh[64 * 72];   // K; overwritten with gated P after QK^T
  __shared__ _Float16 Qh[64 * 72];
  __shared__ _Float16 Vt[64 * 72];
  __shared__ _Float16 Ch[64 * 72];
  __shared__ float cf[64], il[64], ml[64], dl[64], nq[64], nsl[64];

#pragma unroll
  for (int i = 0; i < 2; ++i) {
    int fq = (i << 8) + tid;
    int s = fq >> 3, b8 = (fq & 7) << 3;
    const _Float16* row = Ph + (size_t)(t0 + s) * NPAD + hb;
    f16x8 kv = *(const f16x8*)(row + b8);
    f16x8 qv = *(const f16x8*)(row + 64 + b8);
    f16x8 vv = *(const f16x8*)(row + 128 + b8);
    f16x8 cv = *(const f16x8*)(CS + ((((size_t)(c << 4)) + h) << 12) + ((size_t)s << 6) + b8);
    *(f16x8*)&Kh[s * 72 + b8] = kv;
    *(f16x8*)&Qh[s * 72 + b8] = qv;
    *(f16x8*)&Ch[s * 72 + b8] = cv;
#pragma unroll
    for (int j = 0; j < 8; ++j) Vt[(b8 + j) * 72 + s] = vv[j];
  }
  __syncthreads();

  float iv = 0.f, mt = 0.f, cs = 0.f;
  if (tid < 64) {
    float2 iff = *(const float2*)(IFc + ((size_t)(t0 + tid) << 5) + (h << 1));
    iv = iff.x;
    float fv = iff.y;
    mt = M[(size_t)(t0 + tid) * NH + h];
    nsl[tid] = NS[((size_t)(c << 4) + h) * 64 + tid];
    cs = fv;
#pragma unroll
    for (int dd = 1; dd < 64; dd <<= 1) {
      float o = __shfl_up(cs, dd, 64);
      cs += (tid >= dd) ? o : 0.f;
    }
  }
  __syncthreads();
  if (tid < 64) {
    cf[tid] = cs; il[tid] = iv; ml[tid] = mt;
    float mstart = (c > 0) ? M[(size_t)(t0 - 1) * NH + h] : 0.f;
    dl[tid] = __expf(mstart + cs - mt);
  }
  // nq parallel: 4 threads per row, 16 elems each, 4-lane shfl reduce
  {
    int r = tid >> 2, seg = (tid & 3) << 4;
    float part = 0.f;
#pragma unroll
    for (int j = 0; j < 16; ++j)
      part = fmaf(nsl[seg + j], (float)Qh[r * 72 + seg + j], part);
    part += __shfl_xor(part, 1);
    part += __shfl_xor(part, 2);
    if ((tid & 3) == 0) nq[r] = part;
  }
  __syncthreads();

  int band = wave << 4;
  int arow = lane & 15;
  int kq = (lane >> 4) << 3;
  int crow = (lane >> 4) << 2;

  f16x8 aq0 = *(const f16x8*)&Qh[(band + arow) * 72 + kq];
  f16x8 aq1 = *(const f16x8*)&Qh[(band + arow) * 72 + 32 + kq];

  f32x4 S[4];
  f32x4 zero = {0.f, 0.f, 0.f, 0.f};
#pragma unroll
  for (int n = 0; n < 4; ++n) S[n] = zero;
#pragma unroll
  for (int n = 0; n < 4; ++n) {
    f16x8 b0 = *(const f16x8*)&Kh[((n << 4) + arow) * 72 + kq];
    f16x8 b1 = *(const f16x8*)&Kh[((n << 4) + arow) * 72 + 32 + kq];
    S[n] = __builtin_amdgcn_mfma_f32_16x16x32_f16(aq0, b0, S[n], 0, 0, 0);
    S[n] = __builtin_amdgcn_mfma_f32_16x16x32_f16(aq1, b1, S[n], 0, 0, 0);
  }
  __syncthreads();   // all Kh reads done; Kh region now reusable for P

  float cft[4], mlt[4];
#pragma unroll
  for (int r = 0; r < 4; ++r) {
    int t = band + crow + r;
    cft[r] = cf[t]; mlt[r] = ml[t];
  }
  float rsum[4] = {0.f, 0.f, 0.f, 0.f};
#pragma unroll
  for (int n = 0; n < 4; ++n) {
    int s = (n << 4) + arow;
    float cfs = cf[s], ils = il[s];
#pragma unroll
    for (int r = 0; r < 4; ++r) {
      int t = band + crow + r;
      float w = (s <= t) ? __expf(cft[r] - cfs + ils - mlt[r]) : 0.f;
      float p = S[n][r] * w;
      rsum[r] += p;
      Kh[t * 72 + s] = (_Float16)p;   // P into Kh region
    }
  }
#pragma unroll
  for (int r = 0; r < 4; ++r) {
    float p = rsum[r];
    p += __shfl_xor(p, 1);
    p += __shfl_xor(p, 2);
    p += __shfl_xor(p, 4);
    p += __shfl_xor(p, 8);
    rsum[r] = p;
  }
  __syncthreads();

  f16x8 ap0 = *(const f16x8*)&Kh[(band + arow) * 72 + kq];
  f16x8 ap1 = *(const f16x8*)&Kh[(band + arow) * 72 + 32 + kq];
  f32x4 H[4], I[4];
#pragma unroll
  for (int n = 0; n < 4; ++n) { H[n] = zero; I[n] = zero; }
#pragma unroll
  for (int n = 0; n < 4; ++n) {
    f16x8 bv0 = *(const f16x8*)&Vt[((n << 4) + arow) * 72 + kq];
    f16x8 bv1 = *(const f16x8*)&Vt[((n << 4) + arow) * 72 + 32 + kq];
    H[n] = __builtin_amdgcn_mfma_f32_16x16x32_f16(ap0, bv0, H[n], 0, 0, 0);
    H[n] = __builtin_amdgcn_mfma_f32_16x16x32_f16(ap1, bv1, H[n], 0, 0, 0);
    f16x8 bc0 = *(const f16x8*)&Ch[((n << 4) + arow) * 72 + kq];
    f16x8 bc1 = *(const f16x8*)&Ch[((n << 4) + arow) * 72 + 32 + kq];
    I[n] = __builtin_amdgcn_mfma_f32_16x16x32_f16(aq0, bc0, I[n], 0, 0, 0);
    I[n] = __builtin_amdgcn_mfma_f32_16x16x32_f16(aq1, bc1, I[n], 0, 0, 0);
  }

#pragma unroll
  for (int r = 0; r < 4; ++r) {
    int t = band + crow + r;
    float dt = dl[t];
    float dn = fmaf(dt, nq[t], rsum[r]);
    float rinv = 1.f / fmaxf(fabsf(dn), 1.f);
    float* orow = out + (size_t)(t0 + t) * 1024 + (h << 6);
    const _Float16* og = Ph + (size_t)(t0 + t) * NPAD + hb + 192;
#pragma unroll
    for (int n = 0; n < 4; ++n) {
      int a = (n << 4) + arow;
      float o = 1.f / (1.f + __expf(-(float)og[a]));
      orow[a] = o * (fmaf(dt, I[n][r], H[n][r]) * rinv);
    }
  }
}

// -------------------------------------------------------------------------
extern "C" void kernel_launch(void* const* d_in, const int* in_sizes, int n_in,
                              void* d_out, int out_size, void* d_ws, size_t ws_size,
                              hipStream_t stream) {
  const float* xs   = (const float*)d_in[0];
  const float* ifw  = (const float*)d_in[1];
  const float* ow   = (const float*)d_in[2];
  const float* kqw  = (const float*)d_in[3];
  const float* vw   = (const float*)d_in[4];
  const float* ifb  = (const float*)d_in[5];
  const float* ob   = (const float*)d_in[6];
  const float* kvqb = (const float*)d_in[7];
  float* ws   = (float*)d_ws;
  _Float16* Wph = (_Float16*)(ws + OFF_WP);
  float* BgDC = ws + OFF_BG;
  float* BgDN = BgDC + (size_t)NGRP * 65536;
  float* Ag   = BgDN + (size_t)NGRP * 1024;
  float* bias = ws + OFF_BIAS;
  _Float16* Phm = (_Float16*)(ws + OFF_P);
  float* Mm   = ws + OFF_M;
  _Float16* DCh = (_Float16*)(ws + OFF_DC);
  _Float16* Xh  = (_Float16*)(ws + OFF_DC);  // alias: consumed by gemm before d1 writes DCh
  float* DN   = ws + OFF_DN;
  float* DL   = ws + OFF_DL;
  float* IFc  = ws + OFF_IF;
  float* outp = (float*)d_out;

  hipLaunchKernelGGL(pack_conv, dim3(NPACK + NCONV), dim3(256), 0, stream,
                     ifw, ow, kqw, vw, ifb, ob, kvqb, Wph, bias, xs, Xh);
  hipLaunchKernelGGL(gemm_f16, dim3(33 * 64), dim3(256), 0, stream,
                     Xh, Wph, bias, Phm);
  hipLaunchKernelGGL(gemm_if, dim3(T_LEN / 32), dim3(256), 0, stream, xs, ifw, ifb, IFc);
  hipLaunchKernelGGL(mscan, dim3(NH), dim3(256), 0, stream, IFc, Mm);
  hipLaunchKernelGGL(d1_dc, dim3(NCH * NH), dim3(256), 0, stream, Phm, IFc, Mm, DCh, DN, DL);
  hipLaunchKernelGGL(d2a, dim3(2080), dim3(256), 0, stream, DCh, DN, DL, BgDC, BgDN, Ag);
  hipLaunchKernelGGL(d2c, dim3(2080), dim3(256), 0, stream, DCh, DN, DL, BgDC, BgDN, Ag);
  hipLaunchKernelGGL(d3_out, dim3(NCH * NH), dim3(256), 0, stream, Phm, IFc, Mm, DCh, DN, outp);
}

// Round 17
// 197.978 us; speedup vs baseline: 1.2500x; 1.0549x over previous
//
#include <hip/hip_runtime.h>
#include <math.h>

#define T_LEN 8192
#define D_IN  1024
#define NH    16
#define NPAD  4224   // 32 (i/f) + 16*256 (k,q,v,o per head), padded
#define NCH   128
#define NGRP  8
#define GSZ   16
#define NIF   256    // i/f mini-GEMM blocks (grid HEAD: long pole starts at t=0)
#define NPACK 16896  // pack_w blocks
#define NCONV 4096

typedef __attribute__((ext_vector_type(8))) _Float16 f16x8;
typedef __attribute__((ext_vector_type(4))) _Float16 f16x4;
typedef __attribute__((ext_vector_type(4))) float f32x4;

// ---- workspace layout (float offsets) ----
static const size_t OFF_WP   = 0;                                  // Wph f16 [NPAD][1024] (2.16M floats)
static const size_t OFF_BG   = 2300000;                            // BgDC [8][65536] f32 + BgDN [8][1024] + Ag [8][16]
static const size_t OFF_BIAS = OFF_WP + (size_t)NPAD * D_IN;       // [NPAD] f32
static const size_t OFF_P    = OFF_BIAS + NPAD;                    // Ph f16 [T][NPAD]
static const size_t OFF_M    = OFF_P + (size_t)T_LEN * NPAD;       // [T][16] f32
static const size_t OFF_DC   = OFF_M + (size_t)T_LEN * NH;         // DCh f16 [NCH][16][64][64]; aliases Xh f16 (consumed first)
static const size_t OFF_DN   = OFF_DC + (size_t)NCH * NH * 64 * 64;
static const size_t OFF_DL   = OFF_DN + (size_t)NCH * NH * 64;
static const size_t OFF_IF   = OFF_DL + (size_t)NCH * NH;          // IFc [T][32] f32

__device__ __forceinline__ void glds16(const void* g, void* l) {
  __builtin_amdgcn_global_load_lds(
      (const __attribute__((address_space(1))) void*)g,
      (__attribute__((address_space(3))) void*)l, 16, 0, 0);
}

// -------------------------------------------------------------------------
// Fused front-end.  Block order = execution priority:
//   [0,NIF): fp32-exact i/f mini-GEMM -> IFc  (LONG POLE, starts at t=0)
//   [NIF, NIF+NPACK): pack weights -> Wph/bias (trivial, fills idle CUs)
//   [NIF+NPACK, +NCONV): X -> f16              (trivial)
// R15 lesson: tail placement of the heavy branch serializes; head placement
// overlaps it under the trivial branches' HBM traffic.
// -------------------------------------------------------------------------
__global__ __launch_bounds__(256) void pack_conv_if(
    const float* __restrict__ ifw, const float* __restrict__ ow,
    const float* __restrict__ kqw, const float* __restrict__ vw,
    const float* __restrict__ ifb, const float* __restrict__ ob,
    const float* __restrict__ kvqb, _Float16* __restrict__ Wph,
    float* __restrict__ bias,
    const float* __restrict__ X, _Float16* __restrict__ Xh,
    float* __restrict__ IFc) {
  __shared__ float Xs[32 * 72];
  __shared__ float Ws[32 * 68];
  int b = blockIdx.x;
  int tid = threadIdx.x;
  if (b < NIF) {
    int r0 = b << 5;
    int nc = tid & 15;
    int rg = tid >> 4;
    int n0 = nc << 1;
    int sw = ((n0 >> 3) & 3) << 2;
    int sx = ((rg >> 1) & 3) << 2;

    float acc[2][2];
    acc[0][0] = acc[0][1] = acc[1][0] = acc[1][1] = 0.f;

    for (int k0 = 0; k0 < D_IN; k0 += 64) {
      __syncthreads();
#pragma unroll
      for (int i = 0; i < 2; ++i) {
        int fi = (i << 8) + tid;
        int row = fi >> 4, kk = (fi & 15) << 2;
        float4 v = *(const float4*)(X + (size_t)(r0 + row) * D_IN + k0 + kk);
        *(float4*)&Xs[row * 72 + (kk ^ (((row >> 2) & 3) << 2))] = v;
      }
#pragma unroll
      for (int i = 0; i < 2; ++i) {
        int fi = (i << 8) + tid;
        int row = fi >> 4, kk = (fi & 15) << 2;
        float4 v = *(const float4*)(ifw + (size_t)row * D_IN + k0 + kk);
        *(float4*)&Ws[row * 68 + (kk ^ (((row >> 3) & 3) << 2))] = v;
      }
      __syncthreads();
#pragma unroll
      for (int k4 = 0; k4 < 64; k4 += 4) {
        float4 w0 = *(const float4*)&Ws[n0 * 68 + (k4 ^ sw)];
        float4 w1 = *(const float4*)&Ws[(n0 + 1) * 68 + (k4 ^ sw)];
#pragma unroll
        for (int j = 0; j < 2; ++j) {
          float4 xv = *(const float4*)&Xs[((rg << 1) + j) * 72 + (k4 ^ sx)];
          acc[j][0] = fmaf(xv.x, w0.x, acc[j][0]);
          acc[j][0] = fmaf(xv.y, w0.y, acc[j][0]);
          acc[j][0] = fmaf(xv.z, w0.z, acc[j][0]);
          acc[j][0] = fmaf(xv.w, w0.w, acc[j][0]);
          acc[j][1] = fmaf(xv.x, w1.x, acc[j][1]);
          acc[j][1] = fmaf(xv.y, w1.y, acc[j][1]);
          acc[j][1] = fmaf(xv.z, w1.z, acc[j][1]);
          acc[j][1] = fmaf(xv.w, w1.w, acc[j][1]);
        }
      }
    }
    float b0 = ifb[n0], b1 = ifb[n0 + 1];
#pragma unroll
    for (int j = 0; j < 2; ++j) {
      int row = r0 + (rg << 1) + j;
      float2 st; st.x = acc[j][0] + b0; st.y = acc[j][1] + b1;
      *(float2*)(IFc + ((size_t)row << 5) + n0) = st;
    }
  } else if (b < NIF + NPACK) {
    int idx = (b - NIF) * 256 + tid;
    int n = idx >> 10, d = idx & 1023;
    float w = 0.f, bb = 0.f;
    if (n < 32) {
      int h = n >> 1, t = n & 1;
      w = ifw[(h * 2 + t) * D_IN + d];
      bb = ifb[h * 2 + t];
    } else if (n < 4128) {
      int r = n - 32;
      int h = r >> 8, j = r & 255;
      if (j < 64)       { w = kqw[(h * 128 + j) * D_IN + d] * 0.125f; bb = kvqb[(h * 3 + 0) * 64 + j]; }
      else if (j < 128) { w = kqw[(h * 128 + j) * D_IN + d];          bb = kvqb[(h * 3 + 2) * 64 + (j - 64)]; }
      else if (j < 192) { w = vw[(h * 64 + (j - 128)) * D_IN + d];    bb = kvqb[(h * 3 + 1) * 64 + (j - 128)]; }
      else              { w = ow[(h * 64 + (j - 192)) * D_IN + d];    bb = ob[h * 64 + (j - 192)]; }
    }
    Wph[(size_t)n * D_IN + d] = (_Float16)w;
    if (d == 0) bias[n] = bb;
  } else {
    int i = ((b - NIF - NPACK) * 256 + tid) << 3;
    float4 v0 = *(const float4*)(X + i);
    float4 v1 = *(const float4*)(X + i + 4);
    f16x8 r;
    r[0] = (_Float16)v0.x; r[1] = (_Float16)v0.y; r[2] = (_Float16)v0.z; r[3] = (_Float16)v0.w;
    r[4] = (_Float16)v1.x; r[5] = (_Float16)v1.y; r[6] = (_Float16)v1.z; r[7] = (_Float16)v1.w;
    *(f16x8*)(Xh + i) = r;
  }
}

// -------------------------------------------------------------------------
// f16 MFMA GEMM: Ph = Xh * Wph^T + bias.  R10/R13-proven: 128x128 tile,
// 2-slot dbuf (32KB), T2 both-sides swizzle, XCD-chunked swizzle.
// -------------------------------------------------------------------------
__global__ __launch_bounds__(256) void gemm_f16(
    const _Float16* __restrict__ Xh, const _Float16* __restrict__ Wph,
    const float* __restrict__ bias, _Float16* __restrict__ Ph) {
  __shared__ _Float16 As[2][128 * 32];
  __shared__ _Float16 Bs[2][128 * 32];
  int tid = threadIdx.x;
  int wave = tid >> 6, lane = tid & 63;
  int wgid = blockIdx.x;
  int virt = (wgid & 7) * 264 + (wgid >> 3);
  int mt = virt / 33, nt = virt % 33;
  int m0 = mt << 7, n0 = nt << 7;
  int wr = wave >> 1, wc = wave & 1;

  f32x4 acc[4][4];
  f32x4 zero = {0.f, 0.f, 0.f, 0.f};
#pragma unroll
  for (int i = 0; i < 4; ++i)
#pragma unroll
    for (int j = 0; j < 4; ++j) acc[i][j] = zero;

  int srow = lane >> 2;
  int scol = (((lane & 3) ^ ((lane >> 3) & 3)) << 3);   // pre-swizzled source slot (T2)
  const _Float16* ga = Xh + (size_t)(m0 + wave * 32 + srow) * D_IN + scol;
  const _Float16* gb = Wph + (size_t)(n0 + wave * 32 + srow) * D_IN + scol;
  int lds0 = (wave * 32) * 32;
  int lds1 = (wave * 32 + 16) * 32;

  int fr = lane & 15;
  int fko = (((lane >> 4) ^ ((fr >> 1) & 3)) << 3);     // swizzled frag-read slot (T2)

  glds16(ga, &As[0][lds0]);
  glds16(ga + 16 * D_IN, &As[0][lds1]);
  glds16(gb, &Bs[0][lds0]);
  glds16(gb + 16 * D_IN, &Bs[0][lds1]);
  __syncthreads();

  int cur = 0;
  for (int k0 = 0; k0 < D_IN; k0 += 32) {
    if (k0 + 32 < D_IN) {
      int kn = k0 + 32;
      glds16(ga + kn, &As[cur ^ 1][lds0]);
      glds16(ga + 16 * D_IN + kn, &As[cur ^ 1][lds1]);
      glds16(gb + kn, &Bs[cur ^ 1][lds0]);
      glds16(gb + 16 * D_IN + kn, &Bs[cur ^ 1][lds1]);
    }
    f16x8 a[4], b[4];
#pragma unroll
    for (int mi = 0; mi < 4; ++mi)
      a[mi] = *(const f16x8*)&As[cur][(wr * 64 + mi * 16 + fr) * 32 + fko];
#pragma unroll
    for (int ni = 0; ni < 4; ++ni)
      b[ni] = *(const f16x8*)&Bs[cur][(wc * 64 + ni * 16 + fr) * 32 + fko];
    __builtin_amdgcn_s_setprio(1);
#pragma unroll
    for (int mi = 0; mi < 4; ++mi)
#pragma unroll
      for (int ni = 0; ni < 4; ++ni)
        acc[mi][ni] = __builtin_amdgcn_mfma_f32_16x16x32_f16(a[mi], b[ni], acc[mi][ni], 0, 0, 0);
    __builtin_amdgcn_s_setprio(0);
    __syncthreads();
    cur ^= 1;
  }

  int cr = (lane >> 4) << 2;
  int cc = lane & 15;
#pragma unroll
  for (int mi = 0; mi < 4; ++mi) {
#pragma unroll
    for (int ni = 0; ni < 4; ++ni) {
      int col = n0 + wc * 64 + ni * 16 + cc;
      float bb = bias[col];
      size_t base = (size_t)(m0 + wr * 64 + mi * 16 + cr) * NPAD + col;
#pragma unroll
      for (int r = 0; r < 4; ++r)
        Ph[base + (size_t)r * NPAD] = (_Float16)(acc[mi][ni][r] + bb);
    }
  }
}

// -------------------------------------------------------------------------
// Parallel m-scan (associative (max,+) compose), 16 blocks x 256 threads.
// -------------------------------------------------------------------------
__global__ __launch_bounds__(256) void mscan(const float* __restrict__ IFc, float* __restrict__ M) {
  int h = blockIdx.x;
  int tid = threadIdx.x;
  int lane = tid & 63, wv = tid >> 6;
  int t0 = tid << 5;
  float F = 0.f, I = -1e30f;
#pragma unroll 8
  for (int u = 0; u < 32; ++u) {
    float2 v = *(const float2*)(IFc + ((size_t)(t0 + u) << 5) + (h << 1));
    I = fmaxf(I + v.y, v.x);
    F += v.y;
  }
#pragma unroll
  for (int d = 1; d < 64; d <<= 1) {
    float Fo = __shfl_up(F, d, 64);
    float Io = __shfl_up(I, d, 64);
    if (lane >= d) { I = fmaxf(Io + F, I); F = Fo + F; }
  }
  __shared__ float sF[4], sI[4];
  if (lane == 63) { sF[wv] = F; sI[wv] = I; }
  float Fe = __shfl_up(F, 1, 64);
  float Ie = __shfl_up(I, 1, 64);
  if (lane == 0) { Fe = 0.f; Ie = -1e30f; }
  __syncthreads();
  float Fp = 0.f, Ip = -1e30f;
  for (int w = 0; w < wv; ++w) { Ip = fmaxf(Ip + sF[w], sI[w]); Fp += sF[w]; }
  float Ft = Fp + Fe;
  float It = fmaxf(Ip + Fe, Ie);
  float m = fmaxf(Ft, It);
#pragma unroll 8
  for (int u = 0; u < 32; ++u) {
    float2 v = *(const float2*)(IFc + ((size_t)(t0 + u) << 5) + (h << 1));
    m = fmaxf(v.y + m, v.x);
    M[(size_t)(t0 + u) * NH + h] = m;
  }
}

// -------------------------------------------------------------------------
// D1 (MFMA): DC[a][b] = sum_s (g_s V[s][a]) K[s][b]; DN parallel over 256.
// -------------------------------------------------------------------------
__global__ __launch_bounds__(256) void d1_dc(
    const _Float16* __restrict__ Ph, const float* __restrict__ IFc,
    const float* __restrict__ M,
    _Float16* __restrict__ DCh, float* __restrict__ DN, float* __restrict__ DL) {
  int c = blockIdx.x >> 4, h = blockIdx.x & 15;
  int t0 = c << 6, hb = 32 + (h << 8);
  int tid = threadIdx.x;
  int lane = tid & 63, wave = tid >> 6;
  __shared__ _Float16 Kt[64 * 72];   // Kt[b][s]
  __shared__ _Float16 Vt[64 * 72];   // Vt[a][s]; reused as Dst[a][b] after compute
  __shared__ float gl[64];
#pragma unroll
  for (int i = 0; i < 2; ++i) {
    int fq = (i << 8) + tid;
    int s = fq >> 3, b8 = (fq & 7) << 3;
    const _Float16* row = Ph + (size_t)(t0 + s) * NPAD + hb;
    f16x8 kv = *(const f16x8*)(row + b8);
    f16x8 vv = *(const f16x8*)(row + 128 + b8);
#pragma unroll
    for (int j = 0; j < 8; ++j) {
      Kt[(b8 + j) * 72 + s] = kv[j];
      Vt[(b8 + j) * 72 + s] = vv[j];
    }
  }
  if (tid < 64) {
    float2 iff = *(const float2*)(IFc + ((size_t)(t0 + tid) << 5) + (h << 1));
    float iv = iff.x, fv = iff.y;
    float cs = fv;
#pragma unroll
    for (int dd = 1; dd < 64; dd <<= 1) {
      float o = __shfl_up(cs, dd, 64);
      cs += (tid >= dd) ? o : 0.f;
    }
    float cumL = __shfl(cs, 63, 64);
    float mL = M[(size_t)(t0 + 63) * NH + h];
    gl[tid] = __expf(cumL - cs + iv - mL);
    if (tid == 0) {
      float mstart = (c > 0) ? M[(size_t)(t0 - 1) * NH + h] : 0.f;
      DL[(c << 4) + h] = __expf(mstart + cumL - mL);
    }
  }
  __syncthreads();
  // DN parallel: 4 threads per output b, 16 elems each, 4-lane shfl reduce
  {
    int b = tid >> 2, seg = (tid & 3) << 4;
    float part = 0.f;
#pragma unroll
    for (int j = 0; j < 16; ++j)
      part = fmaf(gl[seg + j], (float)Kt[b * 72 + seg + j], part);
    part += __shfl_xor(part, 1);
    part += __shfl_xor(part, 2);
    if ((tid & 3) == 0) DN[((size_t)(c << 4) + h) * 64 + b] = part;
  }
  int arow = lane & 15;
  int kq = (lane >> 4) << 3;
  int aR = (wave << 4) + arow;
  f16x8 ag0, ag1;
#pragma unroll
  for (int j = 0; j < 8; ++j) {
    ag0[j] = (_Float16)(gl[kq + j] * (float)Vt[aR * 72 + kq + j]);
    ag1[j] = (_Float16)(gl[32 + kq + j] * (float)Vt[aR * 72 + 32 + kq + j]);
  }
  f32x4 accD[4];
  f32x4 zero = {0.f, 0.f, 0.f, 0.f};
#pragma unroll
  for (int n = 0; n < 4; ++n) accD[n] = zero;
#pragma unroll
  for (int n = 0; n < 4; ++n) {
    f16x8 b0 = *(const f16x8*)&Kt[((n << 4) + arow) * 72 + kq];
    f16x8 b1 = *(const f16x8*)&Kt[((n << 4) + arow) * 72 + 32 + kq];
    accD[n] = __builtin_amdgcn_mfma_f32_16x16x32_f16(ag0, b0, accD[n], 0, 0, 0);
    accD[n] = __builtin_amdgcn_mfma_f32_16x16x32_f16(ag1, b1, accD[n], 0, 0, 0);
  }
  __syncthreads();
  int crow = (lane >> 4) << 2, cc = lane & 15;
#pragma unroll
  for (int n = 0; n < 4; ++n)
#pragma unroll
    for (int r = 0; r < 4; ++r)
      Vt[((wave << 4) + crow + r) * 72 + (n << 4) + cc] = (_Float16)accD[n][r];
  __syncthreads();
  size_t base = ((size_t)(c << 4) + h) << 12;
#pragma unroll
  for (int i = 0; i < 2; ++i) {
    int fq = (i << 8) + tid;
    int a = fq >> 3, b8 = (fq & 7) << 3;
    *(f16x8*)(DCh + base + ((size_t)a << 6) + b8) = *(const f16x8*)&Vt[a * 72 + b8];
  }
}

// -------------------------------------------------------------------------
// D2a: per (group, elem) affine aggregates over the group's 16 chunks.
// -------------------------------------------------------------------------
__global__ __launch_bounds__(256) void d2a(
    const _Float16* __restrict__ DCh, const float* __restrict__ DN,
    const float* __restrict__ DL,
    float* __restrict__ BgDC, float* __restrict__ BgDN, float* __restrict__ Ag) {
  int bid = blockIdx.x, tid = threadIdx.x;
  if (bid < 2048) {
    int linear = (bid << 8) + tid;
    int g = linear >> 16, e = linear & 65535;
    int h = e >> 12;
    float carry = 0.f, a = 1.f;
    size_t idx = (size_t)e + ((size_t)g << 4) * 65536;
    float v = (float)DCh[idx];
    for (int u = 0; u < GSZ; ++u) {
      float dl = DL[(((g << 4) + u) << 4) + h];
      float vn = (u < GSZ - 1) ? (float)DCh[idx + 65536] : 0.f;
      carry = fmaf(dl, carry, v);
      a *= dl;
      v = vn;
      idx += 65536;
    }
    BgDC[((size_t)g << 16) + e] = carry;
    if ((e & 4095) == 0) Ag[(g << 4) + h] = a;
  } else {
    int linear = ((bid - 2048) << 8) + tid;
    int g = linear >> 10, e = linear & 1023;
    int h = e >> 6;
    float carry = 0.f;
    size_t idx = (size_t)e + ((size_t)g << 4) * 1024;
    float v = DN[idx];
    for (int u = 0; u < GSZ; ++u) {
      float dl = DL[(((g << 4) + u) << 4) + h];
      float vn = (u < GSZ - 1) ? DN[idx + 1024] : 0.f;
      carry = fmaf(dl, carry, v);
      v = vn;
      idx += 1024;
    }
    BgDN[(g << 10) + e] = carry;
  }
}

// -------------------------------------------------------------------------
// D2c: inline exclusive group-prefix then in-place exclusive carries.
// -------------------------------------------------------------------------
__global__ __launch_bounds__(256) void d2c(
    _Float16* __restrict__ DCh, float* __restrict__ DN,
    const float* __restrict__ DL,
    const float* __restrict__ BgDC, const float* __restrict__ BgDN,
    const float* __restrict__ Ag) {
  int bid = blockIdx.x, tid = threadIdx.x;
  if (bid < 2048) {
    int linear = (bid << 8) + tid;
    int g = linear >> 16, e = linear & 65535;
    int h = e >> 12;
    float P = 0.f;
    for (int gp = 0; gp < g; ++gp)
      P = fmaf(Ag[(gp << 4) + h], P, BgDC[((size_t)gp << 16) + e]);
    float carry = P;
    size_t idx = (size_t)e + ((size_t)g << 4) * 65536;
    float v = (float)DCh[idx];
    for (int u = 0; u < GSZ; ++u) {
      float dl = DL[(((g << 4) + u) << 4) + h];
      float vn = (u < GSZ - 1) ? (float)DCh[idx + 65536] : 0.f;
      DCh[idx] = (_Float16)carry;
      carry = fmaf(dl, carry, v);
      v = vn;
      idx += 65536;
    }
  } else {
    int linear = ((bid - 2048) << 8) + tid;
    int g = linear >> 10, e = linear & 1023;
    int h = e >> 6;
    float P = 0.f;
    for (int gp = 0; gp < g; ++gp)
      P = fmaf(Ag[(gp << 4) + h], P, BgDN[(gp << 10) + e]);
    float carry = P;
    size_t idx = (size_t)e + ((size_t)g << 4) * 1024;
    float v = DN[idx];
    for (int u = 0; u < GSZ; ++u) {
      float dl = DL[(((g << 4) + u) << 4) + h];
      float vn = (u < GSZ - 1) ? DN[idx + 1024] : 0.f;
      DN[idx] = carry;
      carry = fmaf(dl, carry, v);
      v = vn;
      idx += 1024;
    }
  }
}

// -------------------------------------------------------------------------
// D3 (MFMA): per (chunk,head) outputs.  LDS diet (Pl aliases Kh, O direct).
// -------------------------------------------------------------------------
__global__ __launch_bounds__(256) void d3_out(
    const _Float16* __restrict__ Ph, const float* __restrict__ IFc,
    const float* __restrict__ M,
    const _Float16* __restrict__ CS, const float* __restrict__ NS,
    float* __restrict__ out) {
  int c = blockIdx.x >> 4, h = blockIdx.x & 15;
  int t0 = c << 6, hb = 32 + (h << 8);
  int tid = threadIdx.x;
  int lane = tid & 63, wave = tid >> 6;
  __shared__ _Float16 Kh[64 * 72];   // K; overwritten with gated P after QK^T
  __shared__ _Float16 Qh[64 * 72];
  __shared__ _Float16 Vt[64 * 72];
  __shared__ _Float16 Ch[64 * 72];
  __shared__ float cf[64], il[64], ml[64], dl[64], nq[64], nsl[64];

#pragma unroll
  for (int i = 0; i < 2; ++i) {
    int fq = (i << 8) + tid;
    int s = fq >> 3, b8 = (fq & 7) << 3;
    const _Float16* row = Ph + (size_t)(t0 + s) * NPAD + hb;
    f16x8 kv = *(const f16x8*)(row + b8);
    f16x8 qv = *(const f16x8*)(row + 64 + b8);
    f16x8 vv = *(const f16x8*)(row + 128 + b8);
    f16x8 cv = *(const f16x8*)(CS + ((((size_t)(c << 4)) + h) << 12) + ((size_t)s << 6) + b8);
    *(f16x8*)&Kh[s * 72 + b8] = kv;
    *(f16x8*)&Qh[s * 72 + b8] = qv;
    *(f16x8*)&Ch[s * 72 + b8] = cv;
#pragma unroll
    for (int j = 0; j < 8; ++j) Vt[(b8 + j) * 72 + s] = vv[j];
  }
  __syncthreads();

  float iv = 0.f, mt = 0.f, cs = 0.f;
  if (tid < 64) {
    float2 iff = *(const float2*)(IFc + ((size_t)(t0 + tid) << 5) + (h << 1));
    iv = iff.x;
    float fv = iff.y;
    mt = M[(size_t)(t0 + tid) * NH + h];
    nsl[tid] = NS[((size_t)(c << 4) + h) * 64 + tid];
    cs = fv;
#pragma unroll
    for (int dd = 1; dd < 64; dd <<= 1) {
      float o = __shfl_up(cs, dd, 64);
      cs += (tid >= dd) ? o : 0.f;
    }
  }
  __syncthreads();
  if (tid < 64) {
    cf[tid] = cs; il[tid] = iv; ml[tid] = mt;
    float mstart = (c > 0) ? M[(size_t)(t0 - 1) * NH + h] : 0.f;
    dl[tid] = __expf(mstart + cs - mt);
  }
  // nq parallel: 4 threads per row, 16 elems each, 4-lane shfl reduce
  {
    int r = tid >> 2, seg = (tid & 3) << 4;
    float part = 0.f;
#pragma unroll
    for (int j = 0; j < 16; ++j)
      part = fmaf(nsl[seg + j], (float)Qh[r * 72 + seg + j], part);
    part += __shfl_xor(part, 1);
    part += __shfl_xor(part, 2);
    if ((tid & 3) == 0) nq[r] = part;
  }
  __syncthreads();

  int band = wave << 4;
  int arow = lane & 15;
  int kq = (lane >> 4) << 3;
  int crow = (lane >> 4) << 2;

  f16x8 aq0 = *(const f16x8*)&Qh[(band + arow) * 72 + kq];
  f16x8 aq1 = *(const f16x8*)&Qh[(band + arow) * 72 + 32 + kq];

  f32x4 S[4];
  f32x4 zero = {0.f, 0.f, 0.f, 0.f};
#pragma unroll
  for (int n = 0; n < 4; ++n) S[n] = zero;
#pragma unroll
  for (int n = 0; n < 4; ++n) {
    f16x8 b0 = *(const f16x8*)&Kh[((n << 4) + arow) * 72 + kq];
    f16x8 b1 = *(const f16x8*)&Kh[((n << 4) + arow) * 72 + 32 + kq];
    S[n] = __builtin_amdgcn_mfma_f32_16x16x32_f16(aq0, b0, S[n], 0, 0, 0);
    S[n] = __builtin_amdgcn_mfma_f32_16x16x32_f16(aq1, b1, S[n], 0, 0, 0);
  }
  __syncthreads();   // all Kh reads done; Kh region now reusable for P

  float cft[4], mlt[4];
#pragma unroll
  for (int r = 0; r < 4; ++r) {
    int t = band + crow + r;
    cft[r] = cf[t]; mlt[r] = ml[t];
  }
  float rsum[4] = {0.f, 0.f, 0.f, 0.f};
#pragma unroll
  for (int n = 0; n < 4; ++n) {
    int s = (n << 4) + arow;
    float cfs = cf[s], ils = il[s];
#pragma unroll
    for (int r = 0; r < 4; ++r) {
      int t = band + crow + r;
      float w = (s <= t) ? __expf(cft[r] - cfs + ils - mlt[r]) : 0.f;
      float p = S[n][r] * w;
      rsum[r] += p;
      Kh[t * 72 + s] = (_Float16)p;   // P into Kh region
    }
  }
#pragma unroll
  for (int r = 0; r < 4; ++r) {
    float p = rsum[r];
    p += __shfl_xor(p, 1);
    p += __shfl_xor(p, 2);
    p += __shfl_xor(p, 4);
    p += __shfl_xor(p, 8);
    rsum[r] = p;
  }
  __syncthreads();

  f16x8 ap0 = *(const f16x8*)&Kh[(band + arow) * 72 + kq];
  f16x8 ap1 = *(const f16x8*)&Kh[(band + arow) * 72 + 32 + kq];
  f32x4 H[4], I[4];
#pragma unroll
  for (int n = 0; n < 4; ++n) { H[n] = zero; I[n] = zero; }
#pragma unroll
  for (int n = 0; n < 4; ++n) {
    f16x8 bv0 = *(const f16x8*)&Vt[((n << 4) + arow) * 72 + kq];
    f16x8 bv1 = *(const f16x8*)&Vt[((n << 4) + arow) * 72 + 32 + kq];
    H[n] = __builtin_amdgcn_mfma_f32_16x16x32_f16(ap0, bv0, H[n], 0, 0, 0);
    H[n] = __builtin_amdgcn_mfma_f32_16x16x32_f16(ap1, bv1, H[n], 0, 0, 0);
    f16x8 bc0 = *(const f16x8*)&Ch[((n << 4) + arow) * 72 + kq];
    f16x8 bc1 = *(const f16x8*)&Ch[((n << 4) + arow) * 72 + 32 + kq];
    I[n] = __builtin_amdgcn_mfma_f32_16x16x32_f16(aq0, bc0, I[n], 0, 0, 0);
    I[n] = __builtin_amdgcn_mfma_f32_16x16x32_f16(aq1, bc1, I[n], 0, 0, 0);
  }

#pragma unroll
  for (int r = 0; r < 4; ++r) {
    int t = band + crow + r;
    float dt = dl[t];
    float dn = fmaf(dt, nq[t], rsum[r]);
    float rinv = 1.f / fmaxf(fabsf(dn), 1.f);
    float* orow = out + (size_t)(t0 + t) * 1024 + (h << 6);
    const _Float16* og = Ph + (size_t)(t0 + t) * NPAD + hb + 192;
#pragma unroll
    for (int n = 0; n < 4; ++n) {
      int a = (n << 4) + arow;
      float o = 1.f / (1.f + __expf(-(float)og[a]));
      orow[a] = o * (fmaf(dt, I[n][r], H[n][r]) * rinv);
    }
  }
}

// -------------------------------------------------------------------------
extern "C" void kernel_launch(void* const* d_in, const int* in_sizes, int n_in,
                              void* d_out, int out_size, void* d_ws, size_t ws_size,
                              hipStream_t stream) {
  const float* xs   = (const float*)d_in[0];
  const float* ifw  = (const float*)d_in[1];
  const float* ow   = (const float*)d_in[2];
  const float* kqw  = (const float*)d_in[3];
  const float* vw   = (const float*)d_in[4];
  const float* ifb  = (const float*)d_in[5];
  const float* ob   = (const float*)d_in[6];
  const float* kvqb = (const float*)d_in[7];
  float* ws   = (float*)d_ws;
  _Float16* Wph = (_Float16*)(ws + OFF_WP);
  float* BgDC = ws + OFF_BG;
  float* BgDN = BgDC + (size_t)NGRP * 65536;
  float* Ag   = BgDN + (size_t)NGRP * 1024;
  float* bias = ws + OFF_BIAS;
  _Float16* Phm = (_Float16*)(ws + OFF_P);
  float* Mm   = ws + OFF_M;
  _Float16* DCh = (_Float16*)(ws + OFF_DC);
  _Float16* Xh  = (_Float16*)(ws + OFF_DC);  // alias: consumed by gemm before d1 writes DCh
  float* DN   = ws + OFF_DN;
  float* DL   = ws + OFF_DL;
  float* IFc  = ws + OFF_IF;
  float* outp = (float*)d_out;

  hipLaunchKernelGGL(pack_conv_if, dim3(NIF + NPACK + NCONV), dim3(256), 0, stream,
                     ifw, ow, kqw, vw, ifb, ob, kvqb, Wph, bias, xs, Xh, IFc);
  hipLaunchKernelGGL(gemm_f16, dim3(33 * 64), dim3(256), 0, stream,
                     Xh, Wph, bias, Phm);
  hipLaunchKernelGGL(mscan, dim3(NH), dim3(256), 0, stream, IFc, Mm);
  hipLaunchKernelGGL(d1_dc, dim3(NCH * NH), dim3(256), 0, stream, Phm, IFc, Mm, DCh, DN, DL);
  hipLaunchKernelGGL(d2a, dim3(2080), dim3(256), 0, stream, DCh, DN, DL, BgDC, BgDN, Ag);
  hipLaunchKernelGGL(d2c, dim3(2080), dim3(256), 0, stream, DCh, DN, DL, BgDC, BgDN, Ag);
  hipLaunchKernelGGL(d3_out, dim3(NCH * NH), dim3(256), 0, stream, Phm, IFc, Mm, DCh, DN, outp);
}